// Round 3
// baseline (410.950 us; speedup 1.0000x reference)
//
#include <hip/hip_runtime.h>

// D2Q9 LBM single step: collide (BGK, tau=0.6) -> stream (periodic roll) ->
// obstacle bounce-back -> macro fields. Grid 2048x2048, f32.
// Layouts: f[x][y][9], rho[x][y], u[x][y][2], mask[x][y], out[x][y][12].
//
// Gather formulation: thread (x,y) computes f_new[x,y,i] = f_star[x-ex_i, y-ey_i, i]
// by recomputing the neighbor's post-collision value on the fly. Each (cell,dir)
// f_star is consumed by exactly one destination -> no redundant f traffic; the
// 9x rho/u logical re-reads hit L1/L2 (3-row window ~150 KB << 4 MiB L2/XCD).

#define NX 2048
#define NY 2048
#define WRAP 2047

typedef float floatx4 __attribute__((ext_vector_type(4)));

__global__ __launch_bounds__(256) void lbm_step_kernel(
    const float* __restrict__ f,
    const float* __restrict__ rho,
    const float* __restrict__ u,
    const int*   __restrict__ mask,
    float*       __restrict__ out)
{
    const int y = blockIdx.x * blockDim.x + threadIdx.x;
    const int x = blockIdx.y;

    const int   ex[9] = {0, 1, 0, -1, 0, 1, -1, -1, 1};
    const int   ey[9] = {0, 0, 1, 0, -1, 1, 1, -1, -1};
    const float w9[9] = {4.0f/9.0f,
                         1.0f/9.0f, 1.0f/9.0f, 1.0f/9.0f, 1.0f/9.0f,
                         1.0f/36.0f, 1.0f/36.0f, 1.0f/36.0f, 1.0f/36.0f};
    const float INV_TAU = 1.0f / 0.6f;

    const float2* __restrict__ u2 = reinterpret_cast<const float2*>(u);

    float fn[9];

    // Gather-streamed populations: f_new[x,y,i] = f_star[x-ex, y-ey, i]
    #pragma unroll
    for (int i = 0; i < 9; ++i) {
        const int xs  = (x - ex[i]) & WRAP;
        const int ys  = (y - ey[i]) & WRAP;
        const int idx = xs * NY + ys;
        const float  rn = rho[idx];
        const float2 uv = u2[idx];
        const float eu  = (float)ex[i] * uv.x + (float)ey[i] * uv.y;
        const float usq = uv.x * uv.x + uv.y * uv.y;
        const float feq = w9[i] * rn * (1.0f + 3.0f * eu + 4.5f * eu * eu - 1.5f * usq);
        const float fi  = f[idx * 9 + i];
        fn[i] = fi - (fi - feq) * INV_TAU;
    }

    const int cidx = x * NY + y;

    // Obstacle bounce-back: solid destination cells reflect their OWN
    // post-collision populations (reference applies mask at the cell itself).
    if (mask[cidx]) {
        const float  rn = rho[cidx];
        const float2 uv = u2[cidx];
        const float usq = uv.x * uv.x + uv.y * uv.y;
        float fs[9];
        #pragma unroll
        for (int i = 0; i < 9; ++i) {
            const float eu  = (float)ex[i] * uv.x + (float)ey[i] * uv.y;
            const float feq = w9[i] * rn * (1.0f + 3.0f * eu + 4.5f * eu * eu - 1.5f * usq);
            const float fi  = f[cidx * 9 + i];
            fs[i] = fi - (fi - feq) * INV_TAU;
        }
        const int opp[9] = {0, 3, 4, 1, 2, 7, 8, 5, 6};
        #pragma unroll
        for (int i = 0; i < 9; ++i) fn[i] = fs[opp[i]];
    }

    // Macro fields from post-stream distributions
    const float rhon = fn[0] + fn[1] + fn[2] + fn[3] + fn[4]
                     + fn[5] + fn[6] + fn[7] + fn[8];
    const float uxn = (fn[1] - fn[3] + fn[5] - fn[6] - fn[7] + fn[8]) / rhon;
    const float uyn = (fn[2] - fn[4] + fn[5] + fn[6] - fn[7] - fn[8]) / rhon;

    // out[x][y][0:12] = {fn[0..8], rhon, uxn, uyn}; base byte offset 48*cidx
    // is 16B-aligned. Non-temporal: output is never re-read, keep it out of L2.
    floatx4* o4 = reinterpret_cast<floatx4*>(out + (size_t)cidx * 12);
    floatx4 o0; o0.x = fn[0]; o0.y = fn[1]; o0.z = fn[2]; o0.w = fn[3];
    floatx4 o1; o1.x = fn[4]; o1.y = fn[5]; o1.z = fn[6]; o1.w = fn[7];
    floatx4 o2; o2.x = fn[8]; o2.y = rhon;  o2.z = uxn;   o2.w = uyn;
    __builtin_nontemporal_store(o0, o4 + 0);
    __builtin_nontemporal_store(o1, o4 + 1);
    __builtin_nontemporal_store(o2, o4 + 2);
}

extern "C" void kernel_launch(void* const* d_in, const int* in_sizes, int n_in,
                              void* d_out, int out_size, void* d_ws, size_t ws_size,
                              hipStream_t stream) {
    const float* f    = (const float*)d_in[0];
    const float* rho  = (const float*)d_in[1];
    const float* u    = (const float*)d_in[2];
    const int*   mask = (const int*)d_in[3];
    float* out = (float*)d_out;

    dim3 block(256, 1, 1);
    dim3 grid(NY / 256, NX, 1);
    lbm_step_kernel<<<grid, block, 0, stream>>>(f, rho, u, mask, out);
}

// Round 5
// 376.696 us; speedup vs baseline: 1.0909x; 1.0909x over previous
//
#include <hip/hip_runtime.h>

// D2Q9 LBM single step via LDS exchange: collide (BGK, tau=0.6) -> stream ->
// bounce-back -> macro fields. Grid 2048x2048, f32.
// Layouts: f[x][y][9], rho[x][y], u[x][y][2], mask[x][y], out[x][y][12].
//
// Round-3 lesson: gather-form with per-direction global reads is transaction-
// bound (~500 64B-line txns/wave, 27% HBM, VALU 12%). This version makes every
// global access lane-contiguous:
//   P1: element-parallel (halo-cell,dir) -> f* into LDS. Element index == f's
//       native [cell][9] layout, so f loads coalesce perfectly; rho/u are
//       9-way lane-broadcast (1-2 lines/wave).
//   P2: per-cell 9-dir gather from LDS (stride-9 words: conflict-free),
//       bounce-back from own cell's f*, macro fields.
//   P3: results staged in LDS (stride-13 pad: conflict-free) then stored as
//       dense contiguous nontemporal float4s.

#define NX 2048
#define NY 2048
#define WRAP 2047
#define TR 4            // tile rows  (x)
#define TC 64           // tile cols  (y)
#define HR (TR + 2)     // halo rows = 6
#define HC (TC + 2)     // halo cols = 66
#define HCELLS (HR * HC)       // 396
#define HELEMS (HCELLS * 9)    // 3564 floats = 14256 B LDS

typedef float floatx4 __attribute__((ext_vector_type(4)));

__global__ __launch_bounds__(256) void lbm_step_kernel(
    const float* __restrict__ f,
    const float* __restrict__ rho,
    const float* __restrict__ u,
    const int*   __restrict__ mask,
    float*       __restrict__ out)
{
    __shared__ float lds[HELEMS];   // P1/P2: f*[cell][9]; P3: out-stage [TR][TC][13]

    const int tid = threadIdx.x;
    const int y0 = blockIdx.x * TC;
    const int x0 = blockIdx.y * TR;
    const float INV_TAU = 1.0f / 0.6f;

    const float2* __restrict__ u2 = reinterpret_cast<const float2*>(u);

    // ---- Phase 1: f* for all halo cells, element-parallel ----
    // ex+1 packed 2b/dir: {0,1,0,-1,0,1,-1,-1,1} -> 0x20919
    // ey+1 packed 2b/dir: {0,0,1,0,-1,1,1,-1,-1} -> 0x2865
    for (int k = tid; k < HELEMS; k += 256) {
        const unsigned cell = (unsigned)k / 9u;
        const int i  = k - (int)cell * 9;
        const unsigned hr = cell / (unsigned)HC;
        const int hc = (int)cell - (int)hr * HC;
        const int xr = (x0 - 1 + (int)hr) & WRAP;
        const int yc = (y0 - 1 + hc) & WRAP;
        const int g  = xr * NY + yc;

        const float  rn = rho[g];
        const float2 uv = u2[g];
        const float  fi = f[(size_t)g * 9 + i];

        const float exf = (float)((int)((0x20919u >> (2 * i)) & 3u) - 1);
        const float eyf = (float)((int)((0x2865u  >> (2 * i)) & 3u) - 1);
        const float wi  = (i == 0) ? (4.0f / 9.0f)
                                   : ((i < 5) ? (1.0f / 9.0f) : (1.0f / 36.0f));
        const float eu  = exf * uv.x + eyf * uv.y;
        const float usq = uv.x * uv.x + uv.y * uv.y;
        const float feq = wi * rn * (1.0f + 3.0f * eu + 4.5f * eu * eu - 1.5f * usq);
        lds[k] = fi - (fi - feq) * INV_TAU;
    }
    __syncthreads();

    // ---- Phase 2: stream-gather from LDS + bounce-back + macro fields ----
    const int r = tid >> 6;        // 0..3
    const int c = tid & 63;        // 0..63
    const int ex9[9]  = {0, 1, 0, -1, 0, 1, -1, -1, 1};
    const int ey9[9]  = {0, 0, 1, 0, -1, 1, 1, -1, -1};
    const int opp9[9] = {0, 3, 4, 1, 2, 7, 8, 5, 6};

    float fn[9];
    #pragma unroll
    for (int i = 0; i < 9; ++i) {
        const int lsrc = (r + 1 - ex9[i]) * HC + (c + 1 - ey9[i]);
        fn[i] = lds[lsrc * 9 + i];
    }

    const int x = x0 + r, y = y0 + c;
    const int cidx = x * NY + y;
    if (mask[cidx]) {
        const int lc = (r + 1) * HC + (c + 1);
        float fs[9];
        #pragma unroll
        for (int i = 0; i < 9; ++i) fs[i] = lds[lc * 9 + i];
        #pragma unroll
        for (int i = 0; i < 9; ++i) fn[i] = fs[opp9[i]];
    }

    const float rhon = fn[0] + fn[1] + fn[2] + fn[3] + fn[4]
                     + fn[5] + fn[6] + fn[7] + fn[8];
    const float uxn = (fn[1] - fn[3] + fn[5] - fn[6] - fn[7] + fn[8]) / rhon;
    const float uyn = (fn[2] - fn[4] + fn[5] + fn[6] - fn[7] - fn[8]) / rhon;

    __syncthreads();   // all P2 LDS reads done before overwrite

    // ---- Phase 2b: stage 12 outputs per cell, stride 13 (conflict-free) ----
    {
        const int b = tid * 13;    // max 255*13+11 = 3326 < 3564
        #pragma unroll
        for (int i = 0; i < 9; ++i) lds[b + i] = fn[i];
        lds[b + 9]  = rhon;
        lds[b + 10] = uxn;
        lds[b + 11] = uyn;
    }
    __syncthreads();

    // ---- Phase 3: dense contiguous nontemporal float4 stores ----
    // out rows are contiguous: row r2 covers ((x0+r2)*NY + y0)*12 .. +768 floats.
    for (int k4 = tid; k4 < TR * TC * 3; k4 += 256) {   // 768 -> 3 iters
        const unsigned r2  = (unsigned)k4 / 192u;
        const int      rem = k4 - (int)r2 * 192;        // 0..191
        const unsigned cc  = (unsigned)rem / 3u;        // cell in row
        const int      q   = rem - (int)cc * 3;         // which float4 of cell
        const int lbase = (int)r2 * (TC * 13) + (int)cc * 13 + q * 4;
        floatx4 v;
        v.x = lds[lbase + 0];
        v.y = lds[lbase + 1];
        v.z = lds[lbase + 2];
        v.w = lds[lbase + 3];
        const size_t obase = ((size_t)(x0 + (int)r2) * NY + y0) * 12 + (size_t)rem * 4;
        __builtin_nontemporal_store(v, reinterpret_cast<floatx4*>(out + obase));
    }
}

extern "C" void kernel_launch(void* const* d_in, const int* in_sizes, int n_in,
                              void* d_out, int out_size, void* d_ws, size_t ws_size,
                              hipStream_t stream) {
    const float* f    = (const float*)d_in[0];
    const float* rho  = (const float*)d_in[1];
    const float* u    = (const float*)d_in[2];
    const int*   mask = (const int*)d_in[3];
    float* out = (float*)d_out;

    dim3 block(256, 1, 1);
    dim3 grid(NY / TC, NX / TR, 1);   // 32 x 512
    lbm_step_kernel<<<grid, block, 0, stream>>>(f, rho, u, mask, out);
}

// Round 6
// 349.433 us; speedup vs baseline: 1.1760x; 1.0780x over previous
//
#include <hip/hip_runtime.h>

// D2Q9 LBM single step via LDS exchange: collide (BGK, tau=0.6) -> stream ->
// bounce-back -> macro fields. Grid 2048x2048, f32.
// Layouts: f[x][y][9], rho[x][y], u[x][y][2], mask[x][y], out[x][y][12].
//
// R3 lesson: per-direction global gather is txn-bound (27% HBM, 179us).
// R5 lesson: LDS exchange fixes traffic (WRITE exactly ideal) but element
//   loop is VALU-bound (59% busy, 146us). This round: halo amp 1.55->1.29
//   (8x64 tile, 512 thr), per-cell feq algebra hoisted to a cell-parallel
//   pass {A,Bx,By,D}, f prefetched to registers so the element loop is
//   pure LDS+VALU with ~7 FP ops.
//   feq_i = w_i*(A + t + t*t*D),  t = Bx*ex_i + By*ey_i
//   A = rho - 1.5*rho*u^2, Bx = 3*rho*ux, By = 3*rho*uy, D = 1/(2*rho)

#define NX 2048
#define NY 2048
#define WRAP 2047
#define TR 8            // tile rows (x)
#define TC 64           // tile cols (y)
#define NT 512          // threads
#define HR (TR + 2)     // 10
#define HC (TC + 2)     // 66
#define HCELLS (HR * HC)        // 660
#define HELEMS (HCELLS * 9)     // 5940 floats (f* region)
#define CACHEF (HCELLS * 4)     // 2640 floats (cell cache region)
#define FP_ITERS 12             // ceil(5940/512)
#define STAGE_WORDS (NT * 13)   // 6656 <= 5940+2640

typedef float floatx4 __attribute__((ext_vector_type(4)));

__global__ __launch_bounds__(NT) void lbm_step_kernel(
    const float* __restrict__ f,
    const float* __restrict__ rho,
    const float* __restrict__ u,
    const int*   __restrict__ mask,
    float*       __restrict__ out)
{
    __shared__ float lds[HELEMS + CACHEF];   // 34320 B
    floatx4* cache = reinterpret_cast<floatx4*>(lds + HELEMS);  // 16B-aligned

    const int tid = threadIdx.x;
    const int y0 = blockIdx.x * TC;
    const int x0 = blockIdx.y * TR;
    const float INV_TAU = 1.0f / 0.6f;

    const float2* __restrict__ u2 = reinterpret_cast<const float2*>(u);

    // ---- Prefetch f for all halo elements (coalesced; latency hides under
    //      the cell pass). Element index k maps 1:1 onto f's [cell][9] layout.
    float fpre[FP_ITERS];
    #pragma unroll
    for (int it = 0; it < FP_ITERS; ++it) {
        const int k = tid + it * NT;
        if (k < HELEMS) {
            const unsigned cell = (unsigned)k / 9u;
            const int i  = k - (int)cell * 9;
            const unsigned hr = cell / (unsigned)HC;
            const int hc = (int)cell - (int)hr * HC;
            const int xr = (x0 - 1 + (int)hr) & WRAP;
            const int yc = (y0 - 1 + hc) & WRAP;
            const int g  = xr * NY + yc;
            fpre[it] = f[(size_t)g * 9 + i];
        }
    }

    // Own-cell mask, prefetched early (used in P2).
    const int r = tid >> 6;        // 0..7
    const int c = tid & 63;        // 0..63
    const int cidx = (x0 + r) * NY + (y0 + c);
    const int m = mask[cidx];

    // ---- Cell pass: {A, Bx, By, D} per halo cell ----
    for (int k = tid; k < HCELLS; k += NT) {
        const unsigned hr = (unsigned)k / (unsigned)HC;
        const int hc = k - (int)hr * HC;
        const int xr = (x0 - 1 + (int)hr) & WRAP;
        const int yc = (y0 - 1 + hc) & WRAP;
        const int g  = xr * NY + yc;
        const float  rn = rho[g];
        const float2 uv = u2[g];
        const float usq = uv.x * uv.x + uv.y * uv.y;
        floatx4 v;
        v.x = rn - 1.5f * rn * usq;                 // A
        v.y = 3.0f * rn * uv.x;                     // Bx
        v.z = 3.0f * rn * uv.y;                     // By
        v.w = __builtin_amdgcn_rcpf(rn + rn);       // D = 1/(2 rho)
        cache[k] = v;
    }
    __syncthreads();

    // ---- P1b: f* for all halo elements (pure LDS+VALU) ----
    // ex+1 packed 2b/dir: {0,1,0,-1,0,1,-1,-1,1} -> 0x20919
    // ey+1 packed 2b/dir: {0,0,1,0,-1,1,1,-1,-1} -> 0x2865
    #pragma unroll
    for (int it = 0; it < FP_ITERS; ++it) {
        const int k = tid + it * NT;
        if (k < HELEMS) {
            const unsigned cell = (unsigned)k / 9u;
            const int i  = k - (int)cell * 9;
            const floatx4 v = cache[cell];
            const float exf = (float)((int)((0x20919u >> (2 * i)) & 3u) - 1);
            const float eyf = (float)((int)((0x2865u  >> (2 * i)) & 3u) - 1);
            const float wi  = (i == 0) ? (4.0f / 9.0f)
                                       : ((i < 5) ? (1.0f / 9.0f) : (1.0f / 36.0f));
            const float t   = v.y * exf + v.z * eyf;
            const float feq = wi * (v.x + t + t * t * v.w);
            const float fi  = fpre[it];
            lds[k] = fi - (fi - feq) * INV_TAU;
        }
    }
    __syncthreads();

    // ---- P2: stream-gather from LDS + bounce-back + macro fields ----
    const int ex9[9]  = {0, 1, 0, -1, 0, 1, -1, -1, 1};
    const int ey9[9]  = {0, 0, 1, 0, -1, 1, 1, -1, -1};
    const int opp9[9] = {0, 3, 4, 1, 2, 7, 8, 5, 6};

    float fn[9];
    #pragma unroll
    for (int i = 0; i < 9; ++i) {
        const int lsrc = (r + 1 - ex9[i]) * HC + (c + 1 - ey9[i]);
        fn[i] = lds[lsrc * 9 + i];
    }
    if (m) {
        const int lc = ((r + 1) * HC + (c + 1)) * 9;
        #pragma unroll
        for (int i = 0; i < 9; ++i) fn[i] = lds[lc + opp9[i]];
    }

    const float rhon = fn[0] + fn[1] + fn[2] + fn[3] + fn[4]
                     + fn[5] + fn[6] + fn[7] + fn[8];
    const float irho = __builtin_amdgcn_rcpf(rhon);
    const float uxn = (fn[1] - fn[3] + fn[5] - fn[6] - fn[7] + fn[8]) * irho;
    const float uyn = (fn[2] - fn[4] + fn[5] + fn[6] - fn[7] - fn[8]) * irho;

    __syncthreads();   // all P2 LDS reads done before overwrite

    // ---- P2b: stage 12 outputs per cell, stride 13 (conflict-free) ----
    {
        const int b = tid * 13;    // max 511*13+11 = 6654 < 8580
        #pragma unroll
        for (int i = 0; i < 9; ++i) lds[b + i] = fn[i];
        lds[b + 9]  = rhon;
        lds[b + 10] = uxn;
        lds[b + 11] = uyn;
    }
    __syncthreads();

    // ---- P3: dense contiguous nontemporal float4 stores ----
    #pragma unroll
    for (int it = 0; it < 3; ++it) {               // TR*TC*3 = 1536 = 3*NT exact
        const int k4 = tid + it * NT;
        const unsigned r2  = (unsigned)k4 / 192u;  // row in tile
        const int      rem = k4 - (int)r2 * 192;   // 0..191
        const unsigned cc  = (unsigned)rem / 3u;   // cell in row
        const int      q   = rem - (int)cc * 3;    // float4 index in cell
        const int lbase = (int)r2 * (TC * 13) + (int)cc * 13 + q * 4;
        floatx4 v;
        v.x = lds[lbase + 0];
        v.y = lds[lbase + 1];
        v.z = lds[lbase + 2];
        v.w = lds[lbase + 3];
        const size_t obase = ((size_t)(x0 + (int)r2) * NY + y0) * 12 + (size_t)rem * 4;
        __builtin_nontemporal_store(v, reinterpret_cast<floatx4*>(out + obase));
    }
}

extern "C" void kernel_launch(void* const* d_in, const int* in_sizes, int n_in,
                              void* d_out, int out_size, void* d_ws, size_t ws_size,
                              hipStream_t stream) {
    const float* f    = (const float*)d_in[0];
    const float* rho  = (const float*)d_in[1];
    const float* u    = (const float*)d_in[2];
    const int*   mask = (const int*)d_in[3];
    float* out = (float*)d_out;

    dim3 block(NT, 1, 1);
    dim3 grid(NY / TC, NX / TR, 1);   // 32 x 256
    lbm_step_kernel<<<grid, block, 0, stream>>>(f, rho, u, mask, out);
}

// Round 12
// 349.007 us; speedup vs baseline: 1.1775x; 1.0012x over previous
//
#include <hip/hip_runtime.h>

// D2Q9 LBM single step, LDS exchange, per-CELL decomposition.
// Layouts: f[x][y][9], rho[x][y], u[x][y][2], mask[x][y], out[x][y][12].
//
// R3: global gather is txn-bound (179us). R5: LDS exchange fixes traffic,
// element loop VALU-bound (146us). R6: algebra hoist, still ~1200 VALU/thread
// from per-ELEMENT indexing (128us, 50% VALU, 33% HBM). This round: indexing
// paid per CELL, phase A is a raw tile copy (dwordx4 + ds_write_b128).
//
// LDS f-tile layout: 10 halo rows, row stride 608 floats.
//   offset 0..575   : cells hc=1..64  ((hc-1)*9 + i)  <- bulk, matches global
//   offset 576..584 : cell  hc=0  (left halo)
//   offset 585..593 : cell  hc=65 (right halo)

#define NX 2048
#define NY 2048
#define WRAP 2047
#define TR 8
#define TC 64
#define NT 512
#define HCELLS 660          // 10 * 66
#define RS 608              // LDS row stride (floats); 608*4B % 16 == 0
#define LDSWORDS 6656       // max(10*608=6080, NT*13=6656)

typedef float floatx4 __attribute__((ext_vector_type(4)));

__global__ __launch_bounds__(NT, 8) void lbm_step_kernel(
    const float* __restrict__ f,
    const float* __restrict__ rho,
    const float* __restrict__ u,
    const int*   __restrict__ mask,
    float*       __restrict__ out)
{
    __shared__ __align__(16) float buf[LDSWORDS];

    const int tid = threadIdx.x;
    const int y0 = blockIdx.x * TC;
    const int x0 = blockIdx.y * TR;

    const float2* __restrict__ u2 = reinterpret_cast<const float2*>(u);

    // ---------- issue all global loads up front ----------
    // Bulk f: 10 rows x 144 float4 = 1440, contiguous & 16B-aligned per row.
    floatx4 bulkv[3];
    int bulkdst[3] = {-1, -1, -1};
    #pragma unroll
    for (int it = 0; it < 3; ++it) {
        const int k4 = tid + it * NT;
        if (k4 < 1440) {
            const int row  = (unsigned)k4 / 144u;
            const int col4 = k4 - row * 144;
            const int xr   = (x0 - 1 + row) & WRAP;
            const int srcf = (xr * NY + y0) * 9 + col4 * 4;
            bulkv[it]   = *reinterpret_cast<const floatx4*>(f + srcf);
            bulkdst[it] = row * RS + col4 * 4;
        }
    }
    // Edge f: 2 halo columns x 10 rows x 9 = 180 elements.
    float edgev = 0.0f; int edgedst = -1;
    if (tid < 180) {
        const int side = tid >= 90;
        const int er   = side ? tid - 90 : tid;
        const int rowE = (unsigned)er / 9u;
        const int i    = er - rowE * 9;
        const int xr   = (x0 - 1 + rowE) & WRAP;
        const int yc   = side ? ((y0 + TC) & WRAP) : ((y0 - 1) & WRAP);
        edgev   = f[(xr * NY + yc) * 9 + i];
        edgedst = rowE * RS + (side ? 585 : 576) + i;
    }
    // rho/u prefetch for this thread's phase-B cells (latency hides under A).
    float rr[2]; float2 uu[2]; int cbase[2] = {-1, -1};
    #pragma unroll
    for (int it = 0; it < 2; ++it) {
        const int k = tid + it * NT;
        if (k < HCELLS) {
            const int hr = (unsigned)k / 66u;
            const int hc = k - hr * 66;
            const int xr = (x0 - 1 + hr) & WRAP;
            const int yc = (y0 - 1 + hc) & WRAP;
            const int g  = xr * NY + yc;
            rr[it] = rho[g];
            uu[it] = u2[g];
            cbase[it] = hr * RS + (hc == 0 ? 576 : (hc == 65 ? 585 : (hc - 1) * 9));
        }
    }
    const int r = tid >> 6;
    const int c = tid & 63;
    const int m = mask[(x0 + r) * NY + (y0 + c)];

    // ---------- phase A: raw f tile -> LDS ----------
    #pragma unroll
    for (int it = 0; it < 3; ++it)
        if (bulkdst[it] >= 0)
            *reinterpret_cast<floatx4*>(&buf[bulkdst[it]]) = bulkv[it];
    if (edgedst >= 0) buf[edgedst] = edgev;
    __syncthreads();

    // ---------- phase B: collide per cell, in place ----------
    // feq_i = (w_i rho) * (C + t_i + 0.5 t_i^2),  t_i = 3(e_i . u),
    // C = 1 - 1.5 u^2.  f* = (1-1/tau) f + (1/tau) feq.
    const float ITAU = 1.0f / 0.6f;
    const float OMT  = 1.0f - ITAU;
    #pragma unroll
    for (int it = 0; it < 2; ++it) {
        if (cbase[it] >= 0) {
            const int b0 = cbase[it];
            float fi[9];
            #pragma unroll
            for (int i = 0; i < 9; ++i) fi[i] = buf[b0 + i];
            const float rn = rr[it];
            const float ux = uu[it].x, uy = uu[it].y;
            const float C  = 1.0f - 1.5f * (ux * ux + uy * uy);
            const float a  = 3.0f * ux, b = 3.0f * uy;
            const float p  = a + b, q = a - b;
            const float ha = 0.5f * a * a, hb = 0.5f * b * b;
            const float hp = 0.5f * p * p, hq = 0.5f * q * q;
            const float Pm = rn * (4.0f / 9.0f);
            const float Ps = rn * (1.0f / 9.0f);
            const float Pd = rn * (1.0f / 36.0f);
            float feq[9];
            feq[0] = Pm * C;                 // e=( 0, 0) t=0
            feq[1] = Ps * (C + a + ha);      // e=( 1, 0) t=+a
            feq[2] = Ps * (C + b + hb);      // e=( 0, 1) t=+b
            feq[3] = Ps * (C - a + ha);      // e=(-1, 0) t=-a
            feq[4] = Ps * (C - b + hb);      // e=( 0,-1) t=-b
            feq[5] = Pd * (C + p + hp);      // e=( 1, 1) t=+p
            feq[6] = Pd * (C - q + hq);      // e=(-1, 1) t=-q
            feq[7] = Pd * (C - p + hp);      // e=(-1,-1) t=-p
            feq[8] = Pd * (C + q + hq);      // e=( 1,-1) t=+q
            #pragma unroll
            for (int i = 0; i < 9; ++i)
                buf[b0 + i] = fmaf(feq[i], ITAU, OMT * fi[i]);
        }
    }
    __syncthreads();

    // ---------- phase C: stream-gather + bounce-back + macro ----------
    // Source halo cell for dir i: row (r+1-ex_i), col (c+1-ey_i).
    const int colmid = c * 9;                          // hc_src = c+1 (interior)
    const int colL   = (c == 0)  ? 576 : (c - 1) * 9;  // hc_src = c   (ey=+1)
    const int colR   = (c == 63) ? 585 : (c + 1) * 9;  // hc_src = c+2 (ey=-1)
    const int rA = r * RS;            // halo row r   (ex=+1)
    const int rB = rA + RS;           // halo row r+1 (ex= 0)
    const int rC = rB + RS;           // halo row r+2 (ex=-1)

    float fn[9];
    fn[0] = buf[rB + colmid + 0];
    fn[1] = buf[rA + colmid + 1];
    fn[2] = buf[rB + colL   + 2];
    fn[3] = buf[rC + colmid + 3];
    fn[4] = buf[rB + colR   + 4];
    fn[5] = buf[rA + colL   + 5];
    fn[6] = buf[rC + colL   + 6];
    fn[7] = buf[rC + colR   + 7];
    fn[8] = buf[rA + colR   + 8];
    if (m) {
        const int ob = rB + colmid;
        const int opp9[9] = {0, 3, 4, 1, 2, 7, 8, 5, 6};
        #pragma unroll
        for (int i = 0; i < 9; ++i) fn[i] = buf[ob + opp9[i]];
    }

    const float rhon = fn[0] + fn[1] + fn[2] + fn[3] + fn[4]
                     + fn[5] + fn[6] + fn[7] + fn[8];
    const float irho = __builtin_amdgcn_rcpf(rhon);
    const float uxn = (fn[1] - fn[3] + fn[5] - fn[6] - fn[7] + fn[8]) * irho;
    const float uyn = (fn[2] - fn[4] + fn[5] + fn[6] - fn[7] - fn[8]) * irho;

    __syncthreads();   // all phase-C LDS reads done before staging overwrite

    // ---------- stage 12 outputs per cell (stride 13: conflict-free) ----------
    {
        const int b0 = tid * 13;   // max 511*13+11 = 6654 < 6656
        #pragma unroll
        for (int i = 0; i < 9; ++i) buf[b0 + i] = fn[i];
        buf[b0 + 9]  = rhon;
        buf[b0 + 10] = uxn;
        buf[b0 + 11] = uyn;
    }
    __syncthreads();

    // ---------- dense contiguous nontemporal float4 stores ----------
    #pragma unroll
    for (int it = 0; it < 3; ++it) {               // TR*TC*3 = 1536 = 3*NT
        const int k4 = tid + it * NT;
        const unsigned r2  = (unsigned)k4 / 192u;  // row in tile
        const int      rem = k4 - (int)r2 * 192;   // 0..191
        const unsigned cc  = (unsigned)rem / 3u;   // cell in row
        const int      q   = rem - (int)cc * 3;    // float4 index in cell
        const int lbase = (int)r2 * (TC * 13) + (int)cc * 13 + q * 4;
        floatx4 v;
        v.x = buf[lbase + 0];
        v.y = buf[lbase + 1];
        v.z = buf[lbase + 2];
        v.w = buf[lbase + 3];
        const size_t obase = ((size_t)(x0 + (int)r2) * NY + y0) * 12 + (size_t)rem * 4;
        __builtin_nontemporal_store(v, reinterpret_cast<floatx4*>(out + obase));
    }
}

extern "C" void kernel_launch(void* const* d_in, const int* in_sizes, int n_in,
                              void* d_out, int out_size, void* d_ws, size_t ws_size,
                              hipStream_t stream) {
    const float* f    = (const float*)d_in[0];
    const float* rho  = (const float*)d_in[1];
    const float* u    = (const float*)d_in[2];
    const int*   mask = (const int*)d_in[3];
    float* out = (float*)d_out;

    dim3 block(NT, 1, 1);
    dim3 grid(NY / TC, NX / TR, 1);   // 32 x 256
    lbm_step_kernel<<<grid, block, 0, stream>>>(f, rho, u, mask, out);
}